// Round 3
// baseline (890.560 us; speedup 1.0000x reference)
//
#include <hip/hip_runtime.h>
#include <math.h>

#define N_NODES 100000
#define N_EDGES 3200000
#define D_IN 512
#define D_OUT 256
#define NBUK 391     // ceil(100000/256) buckets of 256 rows
#define LDA 40       // padded LDS row stride (ushorts): 80 B, breaks pow-2 bank aliasing
#define MAX_BKT 8832 // csr_build sort capacity (mean 8192, +7 sigma)

typedef unsigned short ushort_t;
typedef unsigned int uint_t;

using f32x4 = __attribute__((ext_vector_type(4))) float;
using s16x8 = __attribute__((ext_vector_type(8))) short;
using u32x4 = __attribute__((ext_vector_type(4))) uint_t;

__device__ __forceinline__ ushort_t f2bf(float f) {
    union { float f; uint_t u; } v; v.f = f;
    uint_t r = v.u + 0x7FFFu + ((v.u >> 16) & 1u);   // round-to-nearest-even
    return (ushort_t)(r >> 16);
}
__device__ __forceinline__ float bf2f(uint_t u) {   // low 16 bits = bf16
    union { uint_t u; float f; } v; v.u = u << 16;
    return v.f;
}

// ---------------------------------------------------------------------------
// W [512][256] fp32 -> Wt [256][512] bf16 (transposed for GEMM B-staging)
// ---------------------------------------------------------------------------
__global__ __launch_bounds__(256) void cvt_w(const float* __restrict__ W,
                                             ushort_t* __restrict__ Wt) {
    int idx = blockIdx.x * 256 + threadIdx.x;   // 131072 total
    int k = idx >> 8, n = idx & 255;
    Wt[(size_t)n * D_IN + k] = f2bf(W[idx]);
}

// ---------------------------------------------------------------------------
// pre_sup = x @ W  (fp32 in, bf16 MFMA, bf16 out). 128x128 tile, BK=32,
// 4 waves of 64x64, 16x16x32 bf16 MFMA, LDS rows padded to 40 ushorts.
// ---------------------------------------------------------------------------
__global__ __launch_bounds__(256) void gemm_xw(const float* __restrict__ X,
                                               const ushort_t* __restrict__ Wt,
                                               ushort_t* __restrict__ P) {
    __shared__ ushort_t As[128 * LDA];
    __shared__ ushort_t Bs[128 * LDA];
    const int tid = threadIdx.x;
    const int n0 = blockIdx.x * 128;
    const int m0 = blockIdx.y * 128;
    const int wave = tid >> 6, lane = tid & 63;
    const int quad = lane >> 4, r16 = lane & 15;
    const int wm = (wave >> 1) * 64, wn = (wave & 1) * 64;

    f32x4 acc[4][4] = {};

    for (int k0 = 0; k0 < D_IN; k0 += 32) {
#pragma unroll
        for (int it = 0; it < 2; ++it) {
            int f = tid + it * 256;
            int row = f >> 2, kc = (f & 3) * 8;
            int grow = m0 + row;
            s16x8 av = {};
            if (grow < N_NODES) {
                const float* xp = X + (size_t)grow * D_IN + k0 + kc;
                f32x4 v0 = *(const f32x4*)(xp);
                f32x4 v1 = *(const f32x4*)(xp + 4);
                av[0] = (short)f2bf(v0[0]); av[1] = (short)f2bf(v0[1]);
                av[2] = (short)f2bf(v0[2]); av[3] = (short)f2bf(v0[3]);
                av[4] = (short)f2bf(v1[0]); av[5] = (short)f2bf(v1[1]);
                av[6] = (short)f2bf(v1[2]); av[7] = (short)f2bf(v1[3]);
            }
            *(s16x8*)(&As[row * LDA + kc]) = av;
            s16x8 bv = *(const s16x8*)(Wt + (size_t)(n0 + row) * D_IN + k0 + kc);
            *(s16x8*)(&Bs[row * LDA + kc]) = bv;
        }
        __syncthreads();

        s16x8 a[4], b[4];
#pragma unroll
        for (int i = 0; i < 4; ++i)
            a[i] = *(const s16x8*)(&As[(wm + i * 16 + r16) * LDA + quad * 8]);
#pragma unroll
        for (int j = 0; j < 4; ++j)
            b[j] = *(const s16x8*)(&Bs[(wn + j * 16 + r16) * LDA + quad * 8]);
#pragma unroll
        for (int i = 0; i < 4; ++i)
#pragma unroll
            for (int j = 0; j < 4; ++j)
                acc[i][j] = __builtin_amdgcn_mfma_f32_16x16x32_bf16(a[i], b[j], acc[i][j], 0, 0, 0);
        __syncthreads();
    }

#pragma unroll
    for (int i = 0; i < 4; ++i) {
#pragma unroll
        for (int rr = 0; rr < 4; ++rr) {
            int grow = m0 + wm + i * 16 + quad * 4 + rr;
            if (grow >= N_NODES) continue;
#pragma unroll
            for (int j = 0; j < 4; ++j) {
                int gcol = n0 + wn + j * 16 + r16;
                P[(size_t)grow * D_OUT + gcol] = f2bf(acc[i][j][rr]);
            }
        }
    }
}

// ---------------------------------------------------------------------------
// CSR build, bucketed (bucket = 256 consecutive rows, b = row>>8)
// ---------------------------------------------------------------------------
__global__ __launch_bounds__(256) void bhist(const int* __restrict__ erow,
                                             int* __restrict__ bcnt) {
    __shared__ int l[NBUK];
    for (int b = threadIdx.x; b < NBUK; b += 256) l[b] = 0;
    __syncthreads();
    int base = blockIdx.x * 4096;
#pragma unroll
    for (int i = 0; i < 16; ++i) {
        int e = base + i * 256 + threadIdx.x;
        if (e < N_EDGES) atomicAdd(&l[erow[e] >> 8], 1);
    }
    __syncthreads();
    for (int b = threadIdx.x; b < NBUK; b += 256)
        if (l[b]) atomicAdd(&bcnt[b], l[b]);
}

__global__ void bscan(const int* __restrict__ bcnt, int* __restrict__ bbase,
                      int* __restrict__ bcursor, int* __restrict__ rstart) {
    __shared__ int sc[512];
    int t = threadIdx.x;
    int v = (t < NBUK) ? bcnt[t] : 0;
    sc[t] = v;
    __syncthreads();
    for (int off = 1; off < 512; off <<= 1) {
        int x = (t >= off) ? sc[t - off] : 0;
        __syncthreads();
        sc[t] += x;
        __syncthreads();
    }
    if (t < NBUK) { int excl = sc[t] - v; bbase[t] = excl; bcursor[t] = excl; }
    if (t == 0) { bbase[NBUK] = N_EDGES; rstart[N_NODES] = N_EDGES; }
}

// per-block LDS hist -> contiguous range reservation -> run-wise writes
__global__ __launch_bounds__(256) void bucket_scatter(const int* __restrict__ erow,
                                                      const int* __restrict__ ecol,
                                                      const float* __restrict__ eval,
                                                      int* __restrict__ bcursor,
                                                      uint2* __restrict__ bkt) {
    __shared__ int lcnt[NBUK];
    __shared__ int lbase[NBUK];
    const int t = threadIdx.x;
    for (int b = t; b < NBUK; b += 256) lcnt[b] = 0;
    __syncthreads();
    const int base = blockIdx.x * 4096;
#pragma unroll
    for (int i = 0; i < 16; ++i) {
        int e = base + i * 256 + t;
        if (e < N_EDGES) atomicAdd(&lcnt[erow[e] >> 8], 1);
    }
    __syncthreads();
    for (int b = t; b < NBUK; b += 256) {
        int c = lcnt[b];
        if (c) lbase[b] = atomicAdd(&bcursor[b], c);
        lcnt[b] = 0;
    }
    __syncthreads();
#pragma unroll
    for (int i = 0; i < 16; ++i) {
        int e = base + i * 256 + t;
        if (e < N_EDGES) {
            int r = erow[e];
            int b = r >> 8;
            int off = atomicAdd(&lcnt[b], 1);
            uint2 p;
            p.x = ((uint_t)(r & 255) << 17) | (uint_t)ecol[e];   // lrow(8b)|col(17b)
            p.y = __float_as_uint(eval[e]);
            bkt[lbase[b] + off] = p;
        }
    }
}

// ---------------------------------------------------------------------------
// one block per bucket. v3: counting-sort the bucket's edges by col-chunk
// (col>>9, <196 bins) via a u16 INDEX permutation in LDS (22.8 KB total LDS,
// safely under the 64 KB static limit), then row-scatter in sorted order.
// The atomic row-cursor order approximately follows loop order, so each
// row's CSR segment ends up ~ascending in col. All spmm waves then sweep
// the col space monotonically in near-lockstep -> L2 holds the moving
// window -> each XCD fetches each pre line ~once (436 MB floor vs 755 MB).
// ---------------------------------------------------------------------------
__global__ __launch_bounds__(256) void csr_build(const uint2* __restrict__ bkt,
                                                 const int* __restrict__ bbase,
                                                 int* __restrict__ rstart,
                                                 uint2* __restrict__ csr) {
    __shared__ ushort_t sidx[MAX_BKT];   // 17,664 B: sorted local-index permutation
    __shared__ int hcnt[256];
    __shared__ int sc[256];
    __shared__ int cur[256];
    __shared__ int ccnt[256];            // col-chunk histogram (col>>9)
    __shared__ int ccur[256];            // chunk scan workspace -> cursor
    const int t = threadIdx.x, b = blockIdx.x;
    const int beg = bbase[b], end = bbase[b + 1];
    const int n = end - beg;
    hcnt[t] = 0; ccnt[t] = 0;
    __syncthreads();
    for (int i = beg + t; i < end; i += 256) {
        uint2 u = bkt[i];
        atomicAdd(&hcnt[u.x >> 17], 1);
        atomicAdd(&ccnt[(u.x & 0x1FFFFu) >> 9], 1);
    }
    __syncthreads();
    // fused Hillis-Steele scans: rows (sc) and col-chunks (ccur)
    int v = hcnt[t];
    int cv = ccnt[t];
    sc[t] = v;
    ccur[t] = cv;
    __syncthreads();
    for (int off = 1; off < 256; off <<= 1) {
        int x1 = (t >= off) ? sc[t - off] : 0;
        int x2 = (t >= off) ? ccur[t - off] : 0;
        __syncthreads();
        sc[t] += x1;
        ccur[t] += x2;
        __syncthreads();
    }
    int excl = sc[t] - v;
    int row = b * 256 + t;
    if (row < N_NODES) rstart[row] = beg + excl;
    cur[t] = excl;
    ccur[t] -= cv;                       // exclusive chunk base -> cursor
    __syncthreads();

    if (n <= MAX_BKT) {
        // pass 1: build col-sorted index permutation in LDS
        for (int i = beg + t; i < end; i += 256) {
            uint2 u = bkt[i];
            int ch = (int)((u.x & 0x1FFFFu) >> 9);
            int p = atomicAdd(&ccur[ch], 1);
            sidx[p] = (ushort_t)(i - beg);
        }
        __syncthreads();
        // pass 2: row-scatter in sorted order (bucket window ~70 KB, L2-hot)
        for (int i = t; i < n; i += 256) {
            uint2 u = bkt[beg + (int)sidx[i]];
            int lr = (int)(u.x >> 17);
            int off = atomicAdd(&cur[lr], 1);
            uint2 o;
            o.x = u.x & 0x1FFFFu;
            o.y = u.y;
            csr[beg + off] = o;
        }
    } else {
        // safety fallback (bucket overflow, ~impossible): unsorted scatter
        for (int i = beg + t; i < end; i += 256) {
            uint2 u = bkt[i];
            int lr = (int)(u.x >> 17);
            int off = atomicAdd(&cur[lr], 1);
            uint2 o;
            o.x = u.x & 0x1FFFFu;
            o.y = u.y;
            csr[beg + off] = o;
        }
    }
}

// ---------------------------------------------------------------------------
// SpMM row-gather: 4 nodes per 256-thread block (one wave per node, no
// barriers: per-wave LDS). Half-wave per edge -> dwordx4 per lane, 1 KB/instr.
// Edge lists are ~col-sorted (csr_build v3) -> windowed L2 reuse.
// ---------------------------------------------------------------------------
__global__ __launch_bounds__(256) void spmm_kernel(const uint2* __restrict__ csr,
                                                   const int* __restrict__ row_start,
                                                   const ushort_t* __restrict__ pre,
                                                   const float* __restrict__ bias,
                                                   float* __restrict__ out) {
    __shared__ uint2 epairs[4][64];
    const int wv   = threadIdx.x >> 6;
    const int lane = threadIdx.x & 63;
    const int half = lane >> 5;      // 0: even edge slots, 1: odd edge slots
    const int l32  = lane & 31;      // feature group: owns features l32*8 .. l32*8+7
    const int node = blockIdx.x * 4 + wv;

    const int beg = row_start[node], end = row_start[node + 1];

    float a0 = 0.f, a1 = 0.f, a2 = 0.f, a3 = 0.f;
    float a4 = 0.f, a5 = 0.f, a6 = 0.f, a7 = 0.f;

    for (int base = beg; base < end; base += 64) {
        const int cnt = min(end - base, 64);
        uint2 p0;
        p0.x = 0u; p0.y = 0u;                       // pad: col 0, weight 0.0f
        if (lane < cnt) p0 = csr[base + lane];
        epairs[wv][lane] = p0;                      // same-wave write->read: lgkmcnt only

        const int iters = (cnt + 7) >> 3;           // 8 edges per iteration
        for (int it = 0; it < iters; ++it) {
            const int e0 = it * 8 + half;
            uint2 q0 = epairs[wv][e0 + 0];
            uint2 q1 = epairs[wv][e0 + 2];
            uint2 q2 = epairs[wv][e0 + 4];
            uint2 q3 = epairs[wv][e0 + 6];

            u32x4 g0 = *(const u32x4*)(pre + (((size_t)q0.x) << 8) + l32 * 8);
            u32x4 g1 = *(const u32x4*)(pre + (((size_t)q1.x) << 8) + l32 * 8);
            u32x4 g2 = *(const u32x4*)(pre + (((size_t)q2.x) << 8) + l32 * 8);
            u32x4 g3 = *(const u32x4*)(pre + (((size_t)q3.x) << 8) + l32 * 8);

            const float w0 = __uint_as_float(q0.y);
            const float w1 = __uint_as_float(q1.y);
            const float w2 = __uint_as_float(q2.y);
            const float w3 = __uint_as_float(q3.y);

            a0 = fmaf(w0, bf2f(g0[0] & 0xFFFFu), a0);
            a1 = fmaf(w0, bf2f(g0[0] >> 16),     a1);
            a2 = fmaf(w0, bf2f(g0[1] & 0xFFFFu), a2);
            a3 = fmaf(w0, bf2f(g0[1] >> 16),     a3);
            a4 = fmaf(w0, bf2f(g0[2] & 0xFFFFu), a4);
            a5 = fmaf(w0, bf2f(g0[2] >> 16),     a5);
            a6 = fmaf(w0, bf2f(g0[3] & 0xFFFFu), a6);
            a7 = fmaf(w0, bf2f(g0[3] >> 16),     a7);

            a0 = fmaf(w1, bf2f(g1[0] & 0xFFFFu), a0);
            a1 = fmaf(w1, bf2f(g1[0] >> 16),     a1);
            a2 = fmaf(w1, bf2f(g1[1] & 0xFFFFu), a2);
            a3 = fmaf(w1, bf2f(g1[1] >> 16),     a3);
            a4 = fmaf(w1, bf2f(g1[2] & 0xFFFFu), a4);
            a5 = fmaf(w1, bf2f(g1[2] >> 16),     a5);
            a6 = fmaf(w1, bf2f(g1[3] & 0xFFFFu), a6);
            a7 = fmaf(w1, bf2f(g1[3] >> 16),     a7);

            a0 = fmaf(w2, bf2f(g2[0] & 0xFFFFu), a0);
            a1 = fmaf(w2, bf2f(g2[0] >> 16),     a1);
            a2 = fmaf(w2, bf2f(g2[1] & 0xFFFFu), a2);
            a3 = fmaf(w2, bf2f(g2[1] >> 16),     a3);
            a4 = fmaf(w2, bf2f(g2[2] & 0xFFFFu), a4);
            a5 = fmaf(w2, bf2f(g2[2] >> 16),     a5);
            a6 = fmaf(w2, bf2f(g2[3] & 0xFFFFu), a6);
            a7 = fmaf(w2, bf2f(g2[3] >> 16),     a7);

            a0 = fmaf(w3, bf2f(g3[0] & 0xFFFFu), a0);
            a1 = fmaf(w3, bf2f(g3[0] >> 16),     a1);
            a2 = fmaf(w3, bf2f(g3[1] & 0xFFFFu), a2);
            a3 = fmaf(w3, bf2f(g3[1] >> 16),     a3);
            a4 = fmaf(w3, bf2f(g3[2] & 0xFFFFu), a4);
            a5 = fmaf(w3, bf2f(g3[2] >> 16),     a5);
            a6 = fmaf(w3, bf2f(g3[3] & 0xFFFFu), a6);
            a7 = fmaf(w3, bf2f(g3[3] >> 16),     a7);
        }
    }

    // combine the two half-wave partial sums (even/odd edge slots)
    a0 += __shfl_xor(a0, 32);
    a1 += __shfl_xor(a1, 32);
    a2 += __shfl_xor(a2, 32);
    a3 += __shfl_xor(a3, 32);
    a4 += __shfl_xor(a4, 32);
    a5 += __shfl_xor(a5, 32);
    a6 += __shfl_xor(a6, 32);
    a7 += __shfl_xor(a7, 32);

    // half 0 stores features l32*8..+3, half 1 stores l32*8+4..+7
    const int fbase = l32 * 8 + half * 4;
    const float* bp = bias + fbase;
    float s0 = half ? a4 : a0;
    float s1 = half ? a5 : a1;
    float s2 = half ? a6 : a2;
    float s3 = half ? a7 : a3;
    f32x4 o;
    o[0] = s0 + bp[0]; o[1] = s1 + bp[1]; o[2] = s2 + bp[2]; o[3] = s3 + bp[3];
    *(f32x4*)(out + (size_t)node * D_OUT + fbase) = o;
}

// ---------------------------------------------------------------------------
// Column sum-of-squares, then in-place normalize + softplus
// ---------------------------------------------------------------------------
__global__ __launch_bounds__(256) void colsq_kernel(const float* __restrict__ out,
                                                    float* __restrict__ colsq) {
    const int f = threadIdx.x;
    float s = 0.f;
    for (int i = blockIdx.x; i < N_NODES; i += gridDim.x) {
        float v = out[(size_t)i * D_OUT + f];
        s = fmaf(v, v, s);
    }
    atomicAdd(&colsq[f], s);
}

__global__ __launch_bounds__(256) void finalize_kernel(float* __restrict__ out,
                                                       const float* __restrict__ colsq) {
    __shared__ float inv[256];
    const int t = threadIdx.x;
    float n = sqrtf(colsq[t]);
    inv[t] = 1.0f / fmaxf(n, 1e-12f);
    __syncthreads();
    const size_t total4 = (size_t)N_NODES * D_OUT / 4;
    for (size_t i = (size_t)blockIdx.x * 256 + t; i < total4; i += (size_t)gridDim.x * 256) {
        f32x4 v = ((const f32x4*)out)[i];
        int fbase = (int)((i * 4) & (D_OUT - 1));
        f32x4 o;
#pragma unroll
        for (int c = 0; c < 4; ++c) {
            float x = v[c] * inv[fbase + c];
            float tt = __expf(x);
            float y = __logf(1.0f + tt);
            o[c] = (x > 20.f) ? x : y;
        }
        ((f32x4*)out)[i] = o;
    }
}

// ---------------------------------------------------------------------------
extern "C" void kernel_launch(void* const* d_in, const int* in_sizes, int n_in,
                              void* d_out, int out_size, void* d_ws, size_t ws_size,
                              hipStream_t stream) {
    const float* x    = (const float*)d_in[0];
    const int*   erow = (const int*)d_in[1];
    const int*   ecol = (const int*)d_in[2];
    const float* eval = (const float*)d_in[3];
    const float* W    = (const float*)d_in[4];
    const float* b    = (const float*)d_in[5];
    float* out = (float*)d_out;
    char* ws = (char*)d_ws;

    // workspace layout (~77.5 MB). bkt (25.6 MB) overlays pre (51.2 MB):
    // bkt is dead after csr_build, which completes before gemm_xw launches.
    uint2*    bkt     = (uint2*)   (ws + 0);            // 25,600,000 B (temp)
    ushort_t* pre     = (ushort_t*)(ws + 0);            // 51,200,000 B
    uint2*    csr     = (uint2*)   (ws + 51200000);     // 25,600,000 B
    int*      rstart  = (int*)     (ws + 76800000);     //    400,004 B
    float*    colsq   = (float*)   (ws + 77200016);     //      1,024 B
    int*      bcnt    = (int*)     (ws + 77201040);     //      1,564 B
    int*      bbase   = (int*)     (ws + 77202608);     //      1,568 B
    int*      bcursor = (int*)     (ws + 77204176);     //      1,564 B
    ushort_t* Wt      = (ushort_t*)(ws + 77205760);     //    262,144 B

    (void)hipMemsetAsync(bcnt, 0, NBUK * sizeof(int), stream);
    (void)hipMemsetAsync(colsq, 0, D_OUT * sizeof(float), stream);

    bhist<<<782, 256, 0, stream>>>(erow, bcnt);
    bscan<<<1, 512, 0, stream>>>(bcnt, bbase, bcursor, rstart);
    bucket_scatter<<<782, 256, 0, stream>>>(erow, ecol, eval, bcursor, bkt);
    csr_build<<<NBUK, 256, 0, stream>>>(bkt, bbase, rstart, csr);
    cvt_w<<<512, 256, 0, stream>>>(W, Wt);
    gemm_xw<<<dim3(2, 782), 256, 0, stream>>>(x, Wt, pre);
    spmm_kernel<<<N_NODES / 4, 256, 0, stream>>>(csr, rstart, pre, b, out);
    colsq_kernel<<<512, 256, 0, stream>>>(out, colsq);
    finalize_kernel<<<1024, 256, 0, stream>>>(out, colsq);
}

// Round 4
// 845.313 us; speedup vs baseline: 1.0535x; 1.0535x over previous
//
#include <hip/hip_runtime.h>
#include <math.h>

#define N_NODES 100000
#define N_EDGES 3200000
#define D_IN 512
#define D_OUT 256
#define NBUK 391     // ceil(100000/256) buckets of 256 rows
#define LDA 40       // padded LDS row stride (ushorts): 80 B, breaks pow-2 bank aliasing
#define NREP 8       // colsq replica count (contention spreading)

typedef unsigned short ushort_t;
typedef unsigned int uint_t;

using f32x4 = __attribute__((ext_vector_type(4))) float;
using s16x8 = __attribute__((ext_vector_type(8))) short;
using u32x4 = __attribute__((ext_vector_type(4))) uint_t;

__device__ __forceinline__ ushort_t f2bf(float f) {
    union { float f; uint_t u; } v; v.f = f;
    uint_t r = v.u + 0x7FFFu + ((v.u >> 16) & 1u);   // round-to-nearest-even
    return (ushort_t)(r >> 16);
}
__device__ __forceinline__ float bf2f(uint_t u) {   // low 16 bits = bf16
    union { uint_t u; float f; } v; v.u = u << 16;
    return v.f;
}

// ---------------------------------------------------------------------------
// W [512][256] fp32 -> Wt [256][512] bf16 (transposed for GEMM B-staging)
// ---------------------------------------------------------------------------
__global__ __launch_bounds__(256) void cvt_w(const float* __restrict__ W,
                                             ushort_t* __restrict__ Wt) {
    int idx = blockIdx.x * 256 + threadIdx.x;   // 131072 total
    int k = idx >> 8, n = idx & 255;
    Wt[(size_t)n * D_IN + k] = f2bf(W[idx]);
}

// ---------------------------------------------------------------------------
// pre_sup = x @ W  (fp32 in, bf16 MFMA, bf16 out). 128x128 tile, BK=32,
// 4 waves of 64x64, 16x16x32 bf16 MFMA, LDS rows padded to 40 ushorts.
// v2: ONE block per 128-row panel; the two n-tiles are an inner loop (nt),
// so the 256 KB fp32 X panel is read from HBM once (2nd pass hits L2).
// Halves gemm's dominant X traffic: 410 MB -> 205 MB.
// ---------------------------------------------------------------------------
__global__ __launch_bounds__(256) void gemm_xw(const float* __restrict__ X,
                                               const ushort_t* __restrict__ Wt,
                                               ushort_t* __restrict__ P) {
    __shared__ ushort_t As[128 * LDA];
    __shared__ ushort_t Bs[128 * LDA];
    const int tid = threadIdx.x;
    const int m0 = blockIdx.y * 128;
    const int wave = tid >> 6, lane = tid & 63;
    const int quad = lane >> 4, r16 = lane & 15;
    const int wm = (wave >> 1) * 64, wn = (wave & 1) * 64;

    for (int nt = 0; nt < 2; ++nt) {
        const int n0 = nt * 128;
        f32x4 acc[4][4] = {};

        for (int k0 = 0; k0 < D_IN; k0 += 32) {
#pragma unroll
            for (int it = 0; it < 2; ++it) {
                int f = tid + it * 256;
                int row = f >> 2, kc = (f & 3) * 8;
                int grow = m0 + row;
                s16x8 av = {};
                if (grow < N_NODES) {
                    const float* xp = X + (size_t)grow * D_IN + k0 + kc;
                    f32x4 v0 = *(const f32x4*)(xp);
                    f32x4 v1 = *(const f32x4*)(xp + 4);
                    av[0] = (short)f2bf(v0[0]); av[1] = (short)f2bf(v0[1]);
                    av[2] = (short)f2bf(v0[2]); av[3] = (short)f2bf(v0[3]);
                    av[4] = (short)f2bf(v1[0]); av[5] = (short)f2bf(v1[1]);
                    av[6] = (short)f2bf(v1[2]); av[7] = (short)f2bf(v1[3]);
                }
                *(s16x8*)(&As[row * LDA + kc]) = av;
                s16x8 bv = *(const s16x8*)(Wt + (size_t)(n0 + row) * D_IN + k0 + kc);
                *(s16x8*)(&Bs[row * LDA + kc]) = bv;
            }
            __syncthreads();

            s16x8 a[4], b[4];
#pragma unroll
            for (int i = 0; i < 4; ++i)
                a[i] = *(const s16x8*)(&As[(wm + i * 16 + r16) * LDA + quad * 8]);
#pragma unroll
            for (int j = 0; j < 4; ++j)
                b[j] = *(const s16x8*)(&Bs[(wn + j * 16 + r16) * LDA + quad * 8]);
#pragma unroll
            for (int i = 0; i < 4; ++i)
#pragma unroll
                for (int j = 0; j < 4; ++j)
                    acc[i][j] = __builtin_amdgcn_mfma_f32_16x16x32_bf16(a[i], b[j], acc[i][j], 0, 0, 0);
            __syncthreads();
        }

#pragma unroll
        for (int i = 0; i < 4; ++i) {
#pragma unroll
            for (int rr = 0; rr < 4; ++rr) {
                int grow = m0 + wm + i * 16 + quad * 4 + rr;
                if (grow >= N_NODES) continue;
#pragma unroll
                for (int j = 0; j < 4; ++j) {
                    int gcol = n0 + wn + j * 16 + r16;
                    P[(size_t)grow * D_OUT + gcol] = f2bf(acc[i][j][rr]);
                }
            }
        }
    }
}

// ---------------------------------------------------------------------------
// CSR build, bucketed (bucket = 256 consecutive rows, b = row>>8)
// ---------------------------------------------------------------------------
__global__ __launch_bounds__(256) void bhist(const int* __restrict__ erow,
                                             int* __restrict__ bcnt) {
    __shared__ int l[NBUK];
    for (int b = threadIdx.x; b < NBUK; b += 256) l[b] = 0;
    __syncthreads();
    int base = blockIdx.x * 4096;
#pragma unroll
    for (int i = 0; i < 16; ++i) {
        int e = base + i * 256 + threadIdx.x;
        if (e < N_EDGES) atomicAdd(&l[erow[e] >> 8], 1);
    }
    __syncthreads();
    for (int b = threadIdx.x; b < NBUK; b += 256)
        if (l[b]) atomicAdd(&bcnt[b], l[b]);
}

__global__ void bscan(const int* __restrict__ bcnt, int* __restrict__ bbase,
                      int* __restrict__ bcursor, int* __restrict__ rstart) {
    __shared__ int sc[512];
    int t = threadIdx.x;
    int v = (t < NBUK) ? bcnt[t] : 0;
    sc[t] = v;
    __syncthreads();
    for (int off = 1; off < 512; off <<= 1) {
        int x = (t >= off) ? sc[t - off] : 0;
        __syncthreads();
        sc[t] += x;
        __syncthreads();
    }
    if (t < NBUK) { int excl = sc[t] - v; bbase[t] = excl; bcursor[t] = excl; }
    if (t == 0) { bbase[NBUK] = N_EDGES; rstart[N_NODES] = N_EDGES; }
}

// per-block LDS hist -> contiguous range reservation -> run-wise writes
__global__ __launch_bounds__(256) void bucket_scatter(const int* __restrict__ erow,
                                                      const int* __restrict__ ecol,
                                                      const float* __restrict__ eval,
                                                      int* __restrict__ bcursor,
                                                      uint2* __restrict__ bkt) {
    __shared__ int lcnt[NBUK];
    __shared__ int lbase[NBUK];
    const int t = threadIdx.x;
    for (int b = t; b < NBUK; b += 256) lcnt[b] = 0;
    __syncthreads();
    const int base = blockIdx.x * 4096;
#pragma unroll
    for (int i = 0; i < 16; ++i) {
        int e = base + i * 256 + t;
        if (e < N_EDGES) atomicAdd(&lcnt[erow[e] >> 8], 1);
    }
    __syncthreads();
    for (int b = t; b < NBUK; b += 256) {
        int c = lcnt[b];
        if (c) lbase[b] = atomicAdd(&bcursor[b], c);
        lcnt[b] = 0;
    }
    __syncthreads();
#pragma unroll
    for (int i = 0; i < 16; ++i) {
        int e = base + i * 256 + t;
        if (e < N_EDGES) {
            int r = erow[e];
            int b = r >> 8;
            int off = atomicAdd(&lcnt[b], 1);
            uint2 p;
            p.x = ((uint_t)(r & 255) << 17) | (uint_t)ecol[e];   // lrow(8b)|col(17b)
            p.y = __float_as_uint(eval[e]);
            bkt[lbase[b] + off] = p;
        }
    }
}

// one block per bucket: LDS row-hist + scan (produces row_start), then
// scatter into this bucket's ~65 KB csr window. (Col-sort removed: measured
// zero FETCH delta — the 32-edge/row order-statistic window (~8.7 MB) never
// fits the 4 MB per-XCD L2, so within-row ordering cannot create locality.)
// ---------------------------------------------------------------------------
__global__ __launch_bounds__(256) void csr_build(const uint2* __restrict__ bkt,
                                                 const int* __restrict__ bbase,
                                                 int* __restrict__ rstart,
                                                 uint2* __restrict__ csr) {
    __shared__ int hcnt[256];
    __shared__ int sc[256];
    __shared__ int cur[256];
    const int t = threadIdx.x, b = blockIdx.x;
    const int beg = bbase[b], end = bbase[b + 1];
    hcnt[t] = 0;
    __syncthreads();
    for (int i = beg + t; i < end; i += 256)
        atomicAdd(&hcnt[bkt[i].x >> 17], 1);
    __syncthreads();
    int v = hcnt[t];
    sc[t] = v;
    __syncthreads();
    for (int off = 1; off < 256; off <<= 1) {
        int x = (t >= off) ? sc[t - off] : 0;
        __syncthreads();
        sc[t] += x;
        __syncthreads();
    }
    int excl = sc[t] - v;
    int row = b * 256 + t;
    if (row < N_NODES) rstart[row] = beg + excl;
    cur[t] = excl;
    __syncthreads();
    for (int i = beg + t; i < end; i += 256) {
        uint2 u = bkt[i];
        int lr = u.x >> 17;
        int off = atomicAdd(&cur[lr], 1);
        uint2 o;
        o.x = u.x & 0x1FFFFu;
        o.y = u.y;
        csr[beg + off] = o;
    }
}

// ---------------------------------------------------------------------------
// SpMM row-gather: 4 nodes per 256-thread block (one wave per node).
// Half-wave per edge -> dwordx4 per lane, 1 KB/instr, 8-edge unroll.
// v3: fused column sum-of-squares — per-block LDS accumulation, flushed to
// NREP replicated global arrays (removes the 102 MB colsq re-read pass).
// ---------------------------------------------------------------------------
__global__ __launch_bounds__(256) void spmm_kernel(const uint2* __restrict__ csr,
                                                   const int* __restrict__ row_start,
                                                   const ushort_t* __restrict__ pre,
                                                   const float* __restrict__ bias,
                                                   float* __restrict__ out,
                                                   float* __restrict__ colsq) {
    __shared__ uint2 epairs[4][64];
    __shared__ float lcq[256];
    const int wv   = threadIdx.x >> 6;
    const int lane = threadIdx.x & 63;
    const int half = lane >> 5;      // 0: even edge slots, 1: odd edge slots
    const int l32  = lane & 31;      // feature group: owns features l32*8 .. l32*8+7
    const int node = blockIdx.x * 4 + wv;

    lcq[threadIdx.x] = 0.f;
    __syncthreads();

    const int beg = row_start[node], end = row_start[node + 1];

    float a0 = 0.f, a1 = 0.f, a2 = 0.f, a3 = 0.f;
    float a4 = 0.f, a5 = 0.f, a6 = 0.f, a7 = 0.f;

    for (int base = beg; base < end; base += 64) {
        const int cnt = min(end - base, 64);
        uint2 p0;
        p0.x = 0u; p0.y = 0u;                       // pad: col 0, weight 0.0f
        if (lane < cnt) p0 = csr[base + lane];
        epairs[wv][lane] = p0;                      // same-wave write->read: lgkmcnt only

        const int iters = (cnt + 7) >> 3;           // 8 edges per iteration
        for (int it = 0; it < iters; ++it) {
            const int e0 = it * 8 + half;
            uint2 q0 = epairs[wv][e0 + 0];
            uint2 q1 = epairs[wv][e0 + 2];
            uint2 q2 = epairs[wv][e0 + 4];
            uint2 q3 = epairs[wv][e0 + 6];

            u32x4 g0 = *(const u32x4*)(pre + (((size_t)q0.x) << 8) + l32 * 8);
            u32x4 g1 = *(const u32x4*)(pre + (((size_t)q1.x) << 8) + l32 * 8);
            u32x4 g2 = *(const u32x4*)(pre + (((size_t)q2.x) << 8) + l32 * 8);
            u32x4 g3 = *(const u32x4*)(pre + (((size_t)q3.x) << 8) + l32 * 8);

            const float w0 = __uint_as_float(q0.y);
            const float w1 = __uint_as_float(q1.y);
            const float w2 = __uint_as_float(q2.y);
            const float w3 = __uint_as_float(q3.y);

            a0 = fmaf(w0, bf2f(g0[0] & 0xFFFFu), a0);
            a1 = fmaf(w0, bf2f(g0[0] >> 16),     a1);
            a2 = fmaf(w0, bf2f(g0[1] & 0xFFFFu), a2);
            a3 = fmaf(w0, bf2f(g0[1] >> 16),     a3);
            a4 = fmaf(w0, bf2f(g0[2] & 0xFFFFu), a4);
            a5 = fmaf(w0, bf2f(g0[2] >> 16),     a5);
            a6 = fmaf(w0, bf2f(g0[3] & 0xFFFFu), a6);
            a7 = fmaf(w0, bf2f(g0[3] >> 16),     a7);

            a0 = fmaf(w1, bf2f(g1[0] & 0xFFFFu), a0);
            a1 = fmaf(w1, bf2f(g1[0] >> 16),     a1);
            a2 = fmaf(w1, bf2f(g1[1] & 0xFFFFu), a2);
            a3 = fmaf(w1, bf2f(g1[1] >> 16),     a3);
            a4 = fmaf(w1, bf2f(g1[2] & 0xFFFFu), a4);
            a5 = fmaf(w1, bf2f(g1[2] >> 16),     a5);
            a6 = fmaf(w1, bf2f(g1[3] & 0xFFFFu), a6);
            a7 = fmaf(w1, bf2f(g1[3] >> 16),     a7);

            a0 = fmaf(w2, bf2f(g2[0] & 0xFFFFu), a0);
            a1 = fmaf(w2, bf2f(g2[0] >> 16),     a1);
            a2 = fmaf(w2, bf2f(g2[1] & 0xFFFFu), a2);
            a3 = fmaf(w2, bf2f(g2[1] >> 16),     a3);
            a4 = fmaf(w2, bf2f(g2[2] & 0xFFFFu), a4);
            a5 = fmaf(w2, bf2f(g2[2] >> 16),     a5);
            a6 = fmaf(w2, bf2f(g2[3] & 0xFFFFu), a6);
            a7 = fmaf(w2, bf2f(g2[3] >> 16),     a7);

            a0 = fmaf(w3, bf2f(g3[0] & 0xFFFFu), a0);
            a1 = fmaf(w3, bf2f(g3[0] >> 16),     a1);
            a2 = fmaf(w3, bf2f(g3[1] & 0xFFFFu), a2);
            a3 = fmaf(w3, bf2f(g3[1] >> 16),     a3);
            a4 = fmaf(w3, bf2f(g3[2] & 0xFFFFu), a4);
            a5 = fmaf(w3, bf2f(g3[2] >> 16),     a5);
            a6 = fmaf(w3, bf2f(g3[3] & 0xFFFFu), a6);
            a7 = fmaf(w3, bf2f(g3[3] >> 16),     a7);
        }
    }

    // combine the two half-wave partial sums (even/odd edge slots)
    a0 += __shfl_xor(a0, 32);
    a1 += __shfl_xor(a1, 32);
    a2 += __shfl_xor(a2, 32);
    a3 += __shfl_xor(a3, 32);
    a4 += __shfl_xor(a4, 32);
    a5 += __shfl_xor(a5, 32);
    a6 += __shfl_xor(a6, 32);
    a7 += __shfl_xor(a7, 32);

    // half 0 stores features l32*8..+3, half 1 stores l32*8+4..+7
    const int fbase = l32 * 8 + half * 4;
    const float* bp = bias + fbase;
    float s0 = half ? a4 : a0;
    float s1 = half ? a5 : a1;
    float s2 = half ? a6 : a2;
    float s3 = half ? a7 : a3;
    f32x4 o;
    o[0] = s0 + bp[0]; o[1] = s1 + bp[1]; o[2] = s2 + bp[2]; o[3] = s3 + bp[3];
    *(f32x4*)(out + (size_t)node * D_OUT + fbase) = o;

    // fused colsq: per-block LDS accumulation of sum(v^2) per column
    atomicAdd(&lcq[fbase + 0], o[0] * o[0]);
    atomicAdd(&lcq[fbase + 1], o[1] * o[1]);
    atomicAdd(&lcq[fbase + 2], o[2] * o[2]);
    atomicAdd(&lcq[fbase + 3], o[3] * o[3]);
    __syncthreads();
    float c = lcq[threadIdx.x];
    if (c != 0.f)
        atomicAdd(&colsq[(blockIdx.x & (NREP - 1)) * 256 + threadIdx.x], c);
}

// ---------------------------------------------------------------------------
// In-place normalize + softplus (colsq = NREP replicated partials)
// ---------------------------------------------------------------------------
__global__ __launch_bounds__(256) void finalize_kernel(float* __restrict__ out,
                                                       const float* __restrict__ colsq) {
    __shared__ float inv[256];
    const int t = threadIdx.x;
    float s = 0.f;
#pragma unroll
    for (int r = 0; r < NREP; ++r) s += colsq[r * 256 + t];
    float n = sqrtf(s);
    inv[t] = 1.0f / fmaxf(n, 1e-12f);
    __syncthreads();
    const size_t total4 = (size_t)N_NODES * D_OUT / 4;
    for (size_t i = (size_t)blockIdx.x * 256 + t; i < total4; i += (size_t)gridDim.x * 256) {
        f32x4 v = ((const f32x4*)out)[i];
        int fbase = (int)((i * 4) & (D_OUT - 1));
        f32x4 o;
#pragma unroll
        for (int c = 0; c < 4; ++c) {
            float x = v[c] * inv[fbase + c];
            float tt = __expf(x);
            float y = __logf(1.0f + tt);
            o[c] = (x > 20.f) ? x : y;
        }
        ((f32x4*)out)[i] = o;
    }
}

// ---------------------------------------------------------------------------
extern "C" void kernel_launch(void* const* d_in, const int* in_sizes, int n_in,
                              void* d_out, int out_size, void* d_ws, size_t ws_size,
                              hipStream_t stream) {
    const float* x    = (const float*)d_in[0];
    const int*   erow = (const int*)d_in[1];
    const int*   ecol = (const int*)d_in[2];
    const float* eval = (const float*)d_in[3];
    const float* W    = (const float*)d_in[4];
    const float* b    = (const float*)d_in[5];
    float* out = (float*)d_out;
    char* ws = (char*)d_ws;

    // workspace layout (~77.5 MB). bkt (25.6 MB) overlays pre (51.2 MB):
    // bkt is dead after csr_build, which completes before gemm_xw launches.
    uint2*    bkt     = (uint2*)   (ws + 0);            // 25,600,000 B (temp)
    ushort_t* pre     = (ushort_t*)(ws + 0);            // 51,200,000 B
    uint2*    csr     = (uint2*)   (ws + 51200000);     // 25,600,000 B
    int*      rstart  = (int*)     (ws + 76800000);     //    400,004 B
    float*    colsq   = (float*)   (ws + 77200016);     //      8,192 B (NREP x 256)
    int*      bcnt    = (int*)     (ws + 77208208);     //      1,564 B
    int*      bbase   = (int*)     (ws + 77209776);     //      1,568 B
    int*      bcursor = (int*)     (ws + 77211344);     //      1,564 B
    ushort_t* Wt      = (ushort_t*)(ws + 77212928);     //    262,144 B

    (void)hipMemsetAsync(bcnt, 0, NBUK * sizeof(int), stream);
    (void)hipMemsetAsync(colsq, 0, NREP * D_OUT * sizeof(float), stream);

    bhist<<<782, 256, 0, stream>>>(erow, bcnt);
    bscan<<<1, 512, 0, stream>>>(bcnt, bbase, bcursor, rstart);
    bucket_scatter<<<782, 256, 0, stream>>>(erow, ecol, eval, bcursor, bkt);
    csr_build<<<NBUK, 256, 0, stream>>>(bkt, bbase, rstart, csr);
    cvt_w<<<512, 256, 0, stream>>>(W, Wt);
    gemm_xw<<<dim3(1, 782), 256, 0, stream>>>(x, Wt, pre);
    spmm_kernel<<<N_NODES / 4, 256, 0, stream>>>(csr, rstart, pre, b, out, colsq);
    finalize_kernel<<<1024, 256, 0, stream>>>(out, colsq);
}

// Round 6
// 839.981 us; speedup vs baseline: 1.0602x; 1.0063x over previous
//
#include <hip/hip_runtime.h>
#include <math.h>

#define N_NODES 100000
#define N_EDGES 3200000
#define D_IN 512
#define D_OUT 256
#define NBUK 391     // ceil(100000/256) buckets of 256 rows
#define LDA 40       // padded LDS row stride (ushorts): 80 B, breaks pow-2 bank aliasing
#define NREP 8       // colsq replica count (contention spreading)

typedef unsigned short ushort_t;
typedef unsigned int uint_t;

using f32x4 = __attribute__((ext_vector_type(4))) float;
using s16x8 = __attribute__((ext_vector_type(8))) short;
using u32x4 = __attribute__((ext_vector_type(4))) uint_t;

// integer RNE f32->bf16 (bit-identical to v_cvt_pk_bf16_f32 rounding);
// proven through rounds 0-4. (hip_bf16.h intrinsics suspected in the
// round-5 container/compile failure — removed.)
__device__ __forceinline__ ushort_t f2bf(float f) {
    union { float f; uint_t u; } v; v.f = f;
    uint_t r = v.u + 0x7FFFu + ((v.u >> 16) & 1u);   // round-to-nearest-even
    return (ushort_t)(r >> 16);
}
__device__ __forceinline__ float bf2f(uint_t u) {   // low 16 bits = bf16
    union { uint_t u; float f; } v; v.u = u << 16;
    return v.f;
}

// ---------------------------------------------------------------------------
// W [512][256] fp32 -> Wt [256][512] bf16 (transposed for GEMM B-staging)
// ---------------------------------------------------------------------------
__global__ __launch_bounds__(256) void cvt_w(const float* __restrict__ W,
                                             ushort_t* __restrict__ Wt) {
    int idx = blockIdx.x * 256 + threadIdx.x;   // 131072 total
    int k = idx >> 8, n = idx & 255;
    Wt[(size_t)n * D_IN + k] = f2bf(W[idx]);
}

// ---------------------------------------------------------------------------
// pre_sup = x @ W  (fp32 in, bf16 MFMA, bf16 out).
// v3: ONE pass per block covers the full 128x256 output: 4 waves in a 2x2
// grid of 64x128 wave-tiles (acc[4][8]). X panel loaded + converted ONCE
// (was twice in v2). Bs holds all 256 Wt rows (LDS total 30.7 KB).
// b-fragment loaded inside j-loop (VGPR cap).
// ---------------------------------------------------------------------------
__global__ __launch_bounds__(256) void gemm_xw(const float* __restrict__ X,
                                               const ushort_t* __restrict__ Wt,
                                               ushort_t* __restrict__ P) {
    __shared__ ushort_t As[128 * LDA];
    __shared__ ushort_t Bs[256 * LDA];
    const int tid = threadIdx.x;
    const int m0 = blockIdx.x * 128;
    const int wave = tid >> 6, lane = tid & 63;
    const int quad = lane >> 4, r16 = lane & 15;
    const int wm = (wave >> 1) * 64;     // {0,64}
    const int wn = (wave & 1) * 128;     // {0,128}

    f32x4 acc[4][8] = {};

    for (int k0 = 0; k0 < D_IN; k0 += 32) {
        // stage A: 128 rows x 32 k of X, fp32 -> bf16
#pragma unroll
        for (int it = 0; it < 2; ++it) {
            int f = tid + it * 256;
            int row = f >> 2, kc = (f & 3) * 8;
            int grow = m0 + row;
            s16x8 av = {};
            if (grow < N_NODES) {
                const float* xp = X + (size_t)grow * D_IN + k0 + kc;
                f32x4 v0 = *(const f32x4*)(xp);
                f32x4 v1 = *(const f32x4*)(xp + 4);
                av[0] = (short)f2bf(v0[0]); av[1] = (short)f2bf(v0[1]);
                av[2] = (short)f2bf(v0[2]); av[3] = (short)f2bf(v0[3]);
                av[4] = (short)f2bf(v1[0]); av[5] = (short)f2bf(v1[1]);
                av[6] = (short)f2bf(v1[2]); av[7] = (short)f2bf(v1[3]);
            }
            *(s16x8*)(&As[row * LDA + kc]) = av;
        }
        // stage B: 256 rows x 32 k of Wt (bf16 passthrough)
#pragma unroll
        for (int it = 0; it < 4; ++it) {
            int f = tid + it * 256;
            int row = f >> 2, kc = (f & 3) * 8;
            s16x8 bv = *(const s16x8*)(Wt + (size_t)row * D_IN + k0 + kc);
            *(s16x8*)(&Bs[row * LDA + kc]) = bv;
        }
        __syncthreads();

        s16x8 a[4];
#pragma unroll
        for (int i = 0; i < 4; ++i)
            a[i] = *(const s16x8*)(&As[(wm + i * 16 + r16) * LDA + quad * 8]);
#pragma unroll
        for (int j = 0; j < 8; ++j) {
            s16x8 b = *(const s16x8*)(&Bs[(wn + j * 16 + r16) * LDA + quad * 8]);
#pragma unroll
            for (int i = 0; i < 4; ++i)
                acc[i][j] = __builtin_amdgcn_mfma_f32_16x16x32_bf16(a[i], b, acc[i][j], 0, 0, 0);
        }
        __syncthreads();
    }

#pragma unroll
    for (int i = 0; i < 4; ++i) {
#pragma unroll
        for (int rr = 0; rr < 4; ++rr) {
            int grow = m0 + wm + i * 16 + quad * 4 + rr;
            if (grow >= N_NODES) continue;
#pragma unroll
            for (int j = 0; j < 8; ++j) {
                int gcol = wn + j * 16 + r16;
                P[(size_t)grow * D_OUT + gcol] = f2bf(acc[i][j][rr]);
            }
        }
    }
}

// ---------------------------------------------------------------------------
// CSR build, bucketed (bucket = 256 consecutive rows, b = row>>8)
// ---------------------------------------------------------------------------
__global__ __launch_bounds__(256) void bhist(const int* __restrict__ erow,
                                             int* __restrict__ bcnt) {
    __shared__ int l[NBUK];
    for (int b = threadIdx.x; b < NBUK; b += 256) l[b] = 0;
    __syncthreads();
    int base = blockIdx.x * 4096;
#pragma unroll
    for (int i = 0; i < 16; ++i) {
        int e = base + i * 256 + threadIdx.x;
        if (e < N_EDGES) atomicAdd(&l[erow[e] >> 8], 1);
    }
    __syncthreads();
    for (int b = threadIdx.x; b < NBUK; b += 256)
        if (l[b]) atomicAdd(&bcnt[b], l[b]);
}

__global__ void bscan(const int* __restrict__ bcnt, int* __restrict__ bbase,
                      int* __restrict__ bcursor, int* __restrict__ rstart) {
    __shared__ int sc[512];
    int t = threadIdx.x;
    int v = (t < NBUK) ? bcnt[t] : 0;
    sc[t] = v;
    __syncthreads();
    for (int off = 1; off < 512; off <<= 1) {
        int x = (t >= off) ? sc[t - off] : 0;
        __syncthreads();
        sc[t] += x;
        __syncthreads();
    }
    if (t < NBUK) { int excl = sc[t] - v; bbase[t] = excl; bcursor[t] = excl; }
    if (t == 0) { bbase[NBUK] = N_EDGES; rstart[N_NODES] = N_EDGES; }
}

// per-block LDS hist -> contiguous range reservation -> run-wise writes
__global__ __launch_bounds__(256) void bucket_scatter(const int* __restrict__ erow,
                                                      const int* __restrict__ ecol,
                                                      const float* __restrict__ eval,
                                                      int* __restrict__ bcursor,
                                                      uint2* __restrict__ bkt) {
    __shared__ int lcnt[NBUK];
    __shared__ int lbase[NBUK];
    const int t = threadIdx.x;
    for (int b = t; b < NBUK; b += 256) lcnt[b] = 0;
    __syncthreads();
    const int base = blockIdx.x * 4096;
#pragma unroll
    for (int i = 0; i < 16; ++i) {
        int e = base + i * 256 + t;
        if (e < N_EDGES) atomicAdd(&lcnt[erow[e] >> 8], 1);
    }
    __syncthreads();
    for (int b = t; b < NBUK; b += 256) {
        int c = lcnt[b];
        if (c) lbase[b] = atomicAdd(&bcursor[b], c);
        lcnt[b] = 0;
    }
    __syncthreads();
#pragma unroll
    for (int i = 0; i < 16; ++i) {
        int e = base + i * 256 + t;
        if (e < N_EDGES) {
            int r = erow[e];
            int b = r >> 8;
            int off = atomicAdd(&lcnt[b], 1);
            uint2 p;
            p.x = ((uint_t)(r & 255) << 17) | (uint_t)ecol[e];   // lrow(8b)|col(17b)
            p.y = __float_as_uint(eval[e]);
            bkt[lbase[b] + off] = p;
        }
    }
}

// one block per bucket: LDS row-hist + scan (produces row_start), then
// scatter into this bucket's ~65 KB csr window
__global__ __launch_bounds__(256) void csr_build(const uint2* __restrict__ bkt,
                                                 const int* __restrict__ bbase,
                                                 int* __restrict__ rstart,
                                                 uint2* __restrict__ csr) {
    __shared__ int hcnt[256];
    __shared__ int sc[256];
    __shared__ int cur[256];
    const int t = threadIdx.x, b = blockIdx.x;
    const int beg = bbase[b], end = bbase[b + 1];
    hcnt[t] = 0;
    __syncthreads();
    for (int i = beg + t; i < end; i += 256)
        atomicAdd(&hcnt[bkt[i].x >> 17], 1);
    __syncthreads();
    int v = hcnt[t];
    sc[t] = v;
    __syncthreads();
    for (int off = 1; off < 256; off <<= 1) {
        int x = (t >= off) ? sc[t - off] : 0;
        __syncthreads();
        sc[t] += x;
        __syncthreads();
    }
    int excl = sc[t] - v;
    int row = b * 256 + t;
    if (row < N_NODES) rstart[row] = beg + excl;
    cur[t] = excl;
    __syncthreads();
    for (int i = beg + t; i < end; i += 256) {
        uint2 u = bkt[i];
        int lr = u.x >> 17;
        int off = atomicAdd(&cur[lr], 1);
        uint2 o;
        o.x = u.x & 0x1FFFFu;
        o.y = u.y;
        csr[beg + off] = o;
    }
}

// ---------------------------------------------------------------------------
// SpMM row-gather: 4 waves/block, each wave handles 4 consecutive nodes
// sequentially (grid 6250). Half-wave per edge -> dwordx4 per lane,
// 1 KB/instr, 8-edge unroll. Fused colsq accumulates in REGISTERS across
// the 4 nodes, then one LDS combine + one global atomic per thread
// (colsq flush traffic /4 vs v3: 25.6 -> 6.4 MB).
// ---------------------------------------------------------------------------
__global__ __launch_bounds__(256) void spmm_kernel(const uint2* __restrict__ csr,
                                                   const int* __restrict__ row_start,
                                                   const ushort_t* __restrict__ pre,
                                                   const float* __restrict__ bias,
                                                   float* __restrict__ out,
                                                   float* __restrict__ colsq) {
    __shared__ uint2 epairs[4][64];
    __shared__ float lcq[256];
    const int wv   = threadIdx.x >> 6;
    const int lane = threadIdx.x & 63;
    const int half = lane >> 5;      // 0: even edge slots, 1: odd edge slots
    const int l32  = lane & 31;      // feature group: owns features l32*8 .. l32*8+7
    const int fbase = l32 * 8 + half * 4;

    lcq[threadIdx.x] = 0.f;
    __syncthreads();

    const float* bp = bias + fbase;
    const float b0 = bp[0], b1 = bp[1], b2 = bp[2], b3 = bp[3];
    float c0 = 0.f, c1 = 0.f, c2 = 0.f, c3 = 0.f;

#pragma unroll 1
    for (int s = 0; s < 4; ++s) {
        const int node = blockIdx.x * 16 + wv * 4 + s;
        const int beg = row_start[node], end = row_start[node + 1];

        float a0 = 0.f, a1 = 0.f, a2 = 0.f, a3 = 0.f;
        float a4 = 0.f, a5 = 0.f, a6 = 0.f, a7 = 0.f;

        for (int base = beg; base < end; base += 64) {
            const int cnt = min(end - base, 64);
            uint2 p0;
            p0.x = 0u; p0.y = 0u;                       // pad: col 0, weight 0.0f
            if (lane < cnt) p0 = csr[base + lane];
            epairs[wv][lane] = p0;                      // same-wave write->read

            const int iters = (cnt + 7) >> 3;           // 8 edges per iteration
            for (int it = 0; it < iters; ++it) {
                const int e0 = it * 8 + half;
                uint2 q0 = epairs[wv][e0 + 0];
                uint2 q1 = epairs[wv][e0 + 2];
                uint2 q2 = epairs[wv][e0 + 4];
                uint2 q3 = epairs[wv][e0 + 6];

                u32x4 g0 = *(const u32x4*)(pre + (((size_t)q0.x) << 8) + l32 * 8);
                u32x4 g1 = *(const u32x4*)(pre + (((size_t)q1.x) << 8) + l32 * 8);
                u32x4 g2 = *(const u32x4*)(pre + (((size_t)q2.x) << 8) + l32 * 8);
                u32x4 g3 = *(const u32x4*)(pre + (((size_t)q3.x) << 8) + l32 * 8);

                const float w0 = __uint_as_float(q0.y);
                const float w1 = __uint_as_float(q1.y);
                const float w2 = __uint_as_float(q2.y);
                const float w3 = __uint_as_float(q3.y);

                a0 = fmaf(w0, bf2f(g0[0] & 0xFFFFu), a0);
                a1 = fmaf(w0, bf2f(g0[0] >> 16),     a1);
                a2 = fmaf(w0, bf2f(g0[1] & 0xFFFFu), a2);
                a3 = fmaf(w0, bf2f(g0[1] >> 16),     a3);
                a4 = fmaf(w0, bf2f(g0[2] & 0xFFFFu), a4);
                a5 = fmaf(w0, bf2f(g0[2] >> 16),     a5);
                a6 = fmaf(w0, bf2f(g0[3] & 0xFFFFu), a6);
                a7 = fmaf(w0, bf2f(g0[3] >> 16),     a7);

                a0 = fmaf(w1, bf2f(g1[0] & 0xFFFFu), a0);
                a1 = fmaf(w1, bf2f(g1[0] >> 16),     a1);
                a2 = fmaf(w1, bf2f(g1[1] & 0xFFFFu), a2);
                a3 = fmaf(w1, bf2f(g1[1] >> 16),     a3);
                a4 = fmaf(w1, bf2f(g1[2] & 0xFFFFu), a4);
                a5 = fmaf(w1, bf2f(g1[2] >> 16),     a5);
                a6 = fmaf(w1, bf2f(g1[3] & 0xFFFFu), a6);
                a7 = fmaf(w1, bf2f(g1[3] >> 16),     a7);

                a0 = fmaf(w2, bf2f(g2[0] & 0xFFFFu), a0);
                a1 = fmaf(w2, bf2f(g2[0] >> 16),     a1);
                a2 = fmaf(w2, bf2f(g2[1] & 0xFFFFu), a2);
                a3 = fmaf(w2, bf2f(g2[1] >> 16),     a3);
                a4 = fmaf(w2, bf2f(g2[2] & 0xFFFFu), a4);
                a5 = fmaf(w2, bf2f(g2[2] >> 16),     a5);
                a6 = fmaf(w2, bf2f(g2[3] & 0xFFFFu), a6);
                a7 = fmaf(w2, bf2f(g2[3] >> 16),     a7);

                a0 = fmaf(w3, bf2f(g3[0] & 0xFFFFu), a0);
                a1 = fmaf(w3, bf2f(g3[0] >> 16),     a1);
                a2 = fmaf(w3, bf2f(g3[1] & 0xFFFFu), a2);
                a3 = fmaf(w3, bf2f(g3[1] >> 16),     a3);
                a4 = fmaf(w3, bf2f(g3[2] & 0xFFFFu), a4);
                a5 = fmaf(w3, bf2f(g3[2] >> 16),     a5);
                a6 = fmaf(w3, bf2f(g3[3] & 0xFFFFu), a6);
                a7 = fmaf(w3, bf2f(g3[3] >> 16),     a7);
            }
        }

        // combine the two half-wave partial sums (even/odd edge slots)
        a0 += __shfl_xor(a0, 32);
        a1 += __shfl_xor(a1, 32);
        a2 += __shfl_xor(a2, 32);
        a3 += __shfl_xor(a3, 32);
        a4 += __shfl_xor(a4, 32);
        a5 += __shfl_xor(a5, 32);
        a6 += __shfl_xor(a6, 32);
        a7 += __shfl_xor(a7, 32);

        // half 0 stores features l32*8..+3, half 1 stores l32*8+4..+7
        float s0 = half ? a4 : a0;
        float s1 = half ? a5 : a1;
        float s2 = half ? a6 : a2;
        float s3 = half ? a7 : a3;
        f32x4 o;
        o[0] = s0 + b0; o[1] = s1 + b1; o[2] = s2 + b2; o[3] = s3 + b3;
        *(f32x4*)(out + (size_t)node * D_OUT + fbase) = o;

        c0 = fmaf(o[0], o[0], c0);
        c1 = fmaf(o[1], o[1], c1);
        c2 = fmaf(o[2], o[2], c2);
        c3 = fmaf(o[3], o[3], c3);
    }

    // fused colsq: per-block LDS combine, then one global atomic per thread
    atomicAdd(&lcq[fbase + 0], c0);
    atomicAdd(&lcq[fbase + 1], c1);
    atomicAdd(&lcq[fbase + 2], c2);
    atomicAdd(&lcq[fbase + 3], c3);
    __syncthreads();
    atomicAdd(&colsq[(blockIdx.x & (NREP - 1)) * 256 + threadIdx.x], lcq[threadIdx.x]);
}

// ---------------------------------------------------------------------------
// In-place normalize + softplus (colsq = NREP replicated partials)
// ---------------------------------------------------------------------------
__global__ __launch_bounds__(256) void finalize_kernel(float* __restrict__ out,
                                                       const float* __restrict__ colsq) {
    __shared__ float inv[256];
    const int t = threadIdx.x;
    float s = 0.f;
#pragma unroll
    for (int r = 0; r < NREP; ++r) s += colsq[r * 256 + t];
    float n = sqrtf(s);
    inv[t] = 1.0f / fmaxf(n, 1e-12f);
    __syncthreads();
    const size_t total4 = (size_t)N_NODES * D_OUT / 4;
    for (size_t i = (size_t)blockIdx.x * 256 + t; i < total4; i += (size_t)gridDim.x * 256) {
        f32x4 v = ((const f32x4*)out)[i];
        int fbase = (int)((i * 4) & (D_OUT - 1));
        f32x4 o;
#pragma unroll
        for (int c = 0; c < 4; ++c) {
            float x = v[c] * inv[fbase + c];
            float tt = __expf(x);
            float y = __logf(1.0f + tt);
            o[c] = (x > 20.f) ? x : y;
        }
        ((f32x4*)out)[i] = o;
    }
}

// ---------------------------------------------------------------------------
extern "C" void kernel_launch(void* const* d_in, const int* in_sizes, int n_in,
                              void* d_out, int out_size, void* d_ws, size_t ws_size,
                              hipStream_t stream) {
    const float* x    = (const float*)d_in[0];
    const int*   erow = (const int*)d_in[1];
    const int*   ecol = (const int*)d_in[2];
    const float* eval = (const float*)d_in[3];
    const float* W    = (const float*)d_in[4];
    const float* b    = (const float*)d_in[5];
    float* out = (float*)d_out;
    char* ws = (char*)d_ws;

    // workspace layout (~77.5 MB). bkt (25.6 MB) overlays pre (51.2 MB):
    // bkt is dead after csr_build, which completes before gemm_xw launches.
    uint2*    bkt     = (uint2*)   (ws + 0);            // 25,600,000 B (temp)
    ushort_t* pre     = (ushort_t*)(ws + 0);            // 51,200,000 B
    uint2*    csr     = (uint2*)   (ws + 51200000);     // 25,600,000 B
    int*      rstart  = (int*)     (ws + 76800000);     //    400,004 B
    float*    colsq   = (float*)   (ws + 77200016);     //      8,192 B (NREP x 256)
    int*      bcnt    = (int*)     (ws + 77208208);     //      1,564 B
    int*      bbase   = (int*)     (ws + 77209776);     //      1,568 B
    int*      bcursor = (int*)     (ws + 77211344);     //      1,564 B
    ushort_t* Wt      = (ushort_t*)(ws + 77212928);     //    262,144 B

    (void)hipMemsetAsync(bcnt, 0, NBUK * sizeof(int), stream);
    (void)hipMemsetAsync(colsq, 0, NREP * D_OUT * sizeof(float), stream);

    bhist<<<782, 256, 0, stream>>>(erow, bcnt);
    bscan<<<1, 512, 0, stream>>>(bcnt, bbase, bcursor, rstart);
    bucket_scatter<<<782, 256, 0, stream>>>(erow, ecol, eval, bcursor, bkt);
    csr_build<<<NBUK, 256, 0, stream>>>(bkt, bbase, rstart, csr);
    cvt_w<<<512, 256, 0, stream>>>(W, Wt);
    gemm_xw<<<782, 256, 0, stream>>>(x, Wt, pre);
    spmm_kernel<<<N_NODES / 16, 256, 0, stream>>>(csr, rstart, pre, b, out, colsq);
    finalize_kernel<<<1024, 256, 0, stream>>>(out, colsq);
}